// Round 3
// baseline (187.411 us; speedup 1.0000x reference)
//
#include <hip/hip_runtime.h>
#include <hip/hip_bf16.h>

typedef __bf16 bf16x8 __attribute__((ext_vector_type(8)));
typedef float  f32x4  __attribute__((ext_vector_type(4)));

#define MFMA32(acc, a, b) acc = __builtin_amdgcn_mfma_f32_16x16x32_bf16(a, b, acc, 0, 0, 0)

__device__ __forceinline__ bf16x8 cvt8(float4 a, float4 b) {
  bf16x8 r;
  r[0] = (__bf16)a.x; r[1] = (__bf16)a.y; r[2] = (__bf16)a.z; r[3] = (__bf16)a.w;
  r[4] = (__bf16)b.x; r[5] = (__bf16)b.y; r[6] = (__bf16)b.z; r[7] = (__bf16)b.w;
  return r;
}

// DPP-based in-row (16-lane) reductions.  row_shr:N = 0x110|N (to-lane-15 reduce,
// OOB lanes read 0 via bound_ctrl), row_ror:N = 0x120|N (all-lane butterfly, no OOB).
template <int CTRL>
__device__ __forceinline__ float dpp_fadd(float x) {
  int yi = __builtin_amdgcn_update_dpp(0, __builtin_bit_cast(int, x), CTRL, 0xF, 0xF, true);
  return x + __builtin_bit_cast(float, yi);
}
template <int CTRL>
__device__ __forceinline__ float dpp_fmax(float x) {
  int yi = __builtin_amdgcn_update_dpp(0, __builtin_bit_cast(int, x), CTRL, 0xF, 0xF, true);
  return fmaxf(x, __builtin_bit_cast(float, yi));
}

// W1frag [ks=4][mt=4][lane][j=8]: A-frag of W1^T:
//   = W1[(ks*32 + (lane>>4)*8 + j)][mt*16 + (lane&15)]
// W2frag [ks2=2][mt2=4][lane][j=8]: A-frag of W2^T with PERMUTED k-axis
//   rho(ks2,g,j) = (ks2*2 + (j>>2))*16 + g*4 + (j&3)   (g = lane>>4)
//   = W2[rho][mt2*16 + (lane&15)]
// Same rho used when building layer-2 B-frags from in-register layer-1 accs.
__global__ void prep_frags(const float* __restrict__ W1,
                           const float* __restrict__ W2,
                           __bf16* __restrict__ wf) {
  int idx = blockIdx.x * 256 + threadIdx.x;
  if (idx < 8192) {
    int j = idx & 7, lane = (idx >> 3) & 63, mt = (idx >> 9) & 3, ks = idx >> 11;
    int i = ks * 32 + ((lane >> 4) << 3) + j;
    int col = mt * 16 + (lane & 15);
    wf[idx] = (__bf16)W1[i * 64 + col];
  } else if (idx < 12288) {
    int t = idx - 8192;
    int j = t & 7, lane = (t >> 3) & 63, mt2 = (t >> 9) & 3, ks2 = (t >> 11) & 1;
    int g = (lane >> 4) & 3;
    int rho = (ks2 * 2 + (j >> 2)) * 16 + g * 4 + (j & 3);
    wf[idx] = (__bf16)W2[rho * 64 + mt2 * 16 + (lane & 15)];
  }
}

// One wave per node, 512 threads = 8 waves/block -> 4 blocks/CU = 32 waves/CU.
// LDS: [0,16384) W1frag  [16384,24576) W2frag
//      [24576,24832) b1 f32  [24832,25088) b2 f32  [25088,25344) w3 f32
__global__ __launch_bounds__(512, 8) void graph_agg(
    const float* __restrict__ emb,
    const float* __restrict__ b1g,
    const float* __restrict__ b2g,
    const float* __restrict__ w3g,
    const float* __restrict__ b3g,
    const int* __restrict__ vn,
    const int* __restrict__ ni,
    const int* __restrict__ nd,
    const __bf16* __restrict__ wf,
    float* __restrict__ out,
    int N) {
  __shared__ __align__(16) unsigned char smem[25344];

  {
    const uint4* src = (const uint4*)wf;
    uint4* dst = (uint4*)smem;
#pragma unroll
    for (int i = 0; i < 3; i++) dst[threadIdx.x + i * 512] = src[threadIdx.x + i * 512];
    int t = threadIdx.x;
    if (t < 64) {
      ((float*)(smem + 24576))[t] = b1g[t];
      ((float*)(smem + 24832))[t] = b2g[t];
      ((float*)(smem + 25088))[t] = w3g[t];
    }
  }
  __syncthreads();

  const __bf16* w1f = (const __bf16*)smem;
  const __bf16* w2f = (const __bf16*)(smem + 16384);
  const int wid = threadIdx.x >> 6;
  const int l   = threadIdx.x & 63;
  const int g   = l >> 4;
  const int lr  = l & 15;
  const float b3v = b3g[0];

  const int gw = blockIdx.x * 8 + wid;
  const int nwaves = gridDim.x * 8;

  int n = gw;
  int node = 0, deg = 0, i0 = 0, i1 = 0;
  if (n < N) {
    node = vn[n]; deg = nd[n];
    i0 = ni[n * 32 + lr]; i1 = ni[n * 32 + 16 + lr];
  }

  for (; n < N; n += nwaves) {
    const int cn = node, cd = deg, ci0 = i0, ci1 = i1;
    {  // prefetch next iteration's scalars/indices
      int nn = n + nwaves; if (nn >= N) nn = n;
      node = vn[nn]; deg = nd[nn];
      i0 = ni[nn * 32 + lr]; i1 = ni[nn * 32 + 16 + lr];
    }
    const float* ub = emb + (long)cn * 64;

    if (cd == 0) {                 // no neighbors: copy own embedding
      out[(long)n * 64 + l] = ub[l];
      continue;
    }
    const bool m1 = (cd > 16);

    int boff = 24576;
    asm volatile("" : "+v"(boff));   // opaque: keep bias reads per-iteration (in LDS, not regs)
    const unsigned char* bb = smem + boff;

    // ---- gather: B-frags of X^T.  ef[nt][ks][j] = e[neigh[nt*16+lr]][ks*32+g*8+j]
    bf16x8 ef[2][2];
    bf16x8 uf[2];
    {
      const bool v = (lr < cd);
      const float* p = emb + (long)(v ? ci0 : cn) * 64 + g * 8;
      float4 a0 = *(const float4*)p,        a1 = *(const float4*)(p + 4);
      float4 c0 = *(const float4*)(p + 32), c1 = *(const float4*)(p + 36);
      if (!v) { a0 = a1 = c0 = c1 = make_float4(0.f, 0.f, 0.f, 0.f); }
      ef[0][0] = cvt8(a0, a1); ef[0][1] = cvt8(c0, c1);
    }
    if (m1) {
      const bool v = (16 + lr < cd);
      const float* p = emb + (long)(v ? ci1 : cn) * 64 + g * 8;
      float4 a0 = *(const float4*)p,        a1 = *(const float4*)(p + 4);
      float4 c0 = *(const float4*)(p + 32), c1 = *(const float4*)(p + 36);
      if (!v) { a0 = a1 = c0 = c1 = make_float4(0.f, 0.f, 0.f, 0.f); }
      ef[1][0] = cvt8(a0, a1); ef[1][1] = cvt8(c0, c1);
    }
    {
      const float* q = ub + g * 8;
      uf[0] = cvt8(*(const float4*)q,        *(const float4*)(q + 4));
      uf[1] = cvt8(*(const float4*)(q + 32), *(const float4*)(q + 36));
    }

    // ---- layer 1: C1t[64][32] = W1^T @ X^T  (acc init = b1 broadcast) ----
    f32x4 acc1[4][2];
#pragma unroll
    for (int mt = 0; mt < 4; mt++) {
      f32x4 bv = *(const f32x4*)(bb + (mt * 16 + g * 4) * 4);
      acc1[mt][0] = bv; acc1[mt][1] = bv;
    }
#pragma unroll
    for (int ks = 0; ks < 4; ks++) {
      bf16x8 xb0 = (ks < 2) ? ef[0][ks] : uf[ks - 2];
#pragma unroll
      for (int mt = 0; mt < 4; mt++) {
        bf16x8 wa = *(const bf16x8*)(w1f + ((ks * 4 + mt) * 64 + l) * 8);
        MFMA32(acc1[mt][0], wa, xb0);
        if (m1) {
          bf16x8 xb1 = (ks < 2) ? ef[1][ks] : uf[ks - 2];
          MFMA32(acc1[mt][1], wa, xb1);
        }
      }
    }

    // ---- relu -> bf16 B-frags for layer 2, permuted k-axis (in-register) ----
    bf16x8 hb[2][2];
#pragma unroll
    for (int ks2 = 0; ks2 < 2; ks2++) {
#pragma unroll
      for (int nt = 0; nt < 2; nt++) {
        if (nt == 0 || m1) {
          bf16x8 v;
#pragma unroll
          for (int j = 0; j < 8; j++) {
            const int mt = ks2 * 2 + (j >> 2), r = j & 3;
            v[j] = (__bf16)fmaxf(acc1[mt][nt][r], 0.f);
          }
          hb[ks2][nt] = v;
        }
      }
    }

    // ---- layer 2: C2t[64][32] = W2^T @ H1t (acc init = b2) ----
    f32x4 acc2[4][2];
#pragma unroll
    for (int mt2 = 0; mt2 < 4; mt2++) {
      f32x4 bv = *(const f32x4*)(bb + 256 + (mt2 * 16 + g * 4) * 4);
      acc2[mt2][0] = bv; acc2[mt2][1] = bv;
    }
#pragma unroll
    for (int ks2 = 0; ks2 < 2; ks2++) {
#pragma unroll
      for (int mt2 = 0; mt2 < 4; mt2++) {
        bf16x8 wa = *(const bf16x8*)(w2f + ((ks2 * 4 + mt2) * 64 + l) * 8);
        MFMA32(acc2[mt2][0], wa, hb[ks2][0]);
        if (m1) MFMA32(acc2[mt2][1], wa, hb[ks2][1]);
      }
    }

    // ---- scores: s[nb] = relu(C2t+b2) . w3 + b3 (partial over 16 in-lane h2 dims) ----
    float sv0 = 0.f, sv1 = 0.f;
    {
#pragma unroll
      for (int mt2 = 0; mt2 < 4; mt2++) {
        f32x4 wv = *(const f32x4*)(bb + 512 + (mt2 * 16 + g * 4) * 4);
#pragma unroll
        for (int r = 0; r < 4; r++) {
          sv0 += fmaxf(acc2[mt2][0][r], 0.f) * wv[r];
          if (m1) sv1 += fmaxf(acc2[mt2][1][r], 0.f) * wv[r];
        }
      }
    }
    sv0 += __shfl_xor(sv0, 16); sv0 += __shfl_xor(sv0, 32);
    if (m1) { sv1 += __shfl_xor(sv1, 16); sv1 += __shfl_xor(sv1, 32); }

    const bool v0 = (lr < cd);
    const bool v1 = m1 && (16 + lr < cd);
    sv0 = v0 ? (sv0 + b3v) : -1e30f;
    sv1 = v1 ? (sv1 + b3v) : -1e30f;

    // ---- softmax over 32 neighbors (neighbor = lr within each 16-row) ----
    float mx = fmaxf(sv0, sv1);
    mx = dpp_fmax<0x128>(mx);   // row_ror:8  (all-lane butterfly within 16)
    mx = dpp_fmax<0x124>(mx);   // row_ror:4
    mx = dpp_fmax<0x122>(mx);   // row_ror:2
    mx = dpp_fmax<0x121>(mx);   // row_ror:1

    float p0 = v0 ? __expf(sv0 - mx) : 0.f;
    float p1 = v1 ? __expf(sv1 - mx) : 0.f;
    float sum = p0 + p1;
    sum = dpp_fadd<0x128>(sum);
    sum = dpp_fadd<0x124>(sum);
    sum = dpp_fadd<0x122>(sum);
    sum = dpp_fadd<0x121>(sum);
    const float inv = 1.f / sum;
    const float a0 = p0 * inv, a1 = p1 * inv;

    // ---- out[d] = sum_k att[k]*e[k][d]: in-lane over nt, DPP row_shr tree over lr
    //      (result lands in lane 15 of each 16-row) ----
    float o[16];
#pragma unroll
    for (int ks = 0; ks < 2; ks++)
#pragma unroll
      for (int j = 0; j < 8; j++) {
        float v = a0 * (float)ef[0][ks][j];
        if (m1) v += a1 * (float)ef[1][ks][j];
        o[ks * 8 + j] = v;
      }
#pragma unroll
    for (int t = 0; t < 16; t++) {
      o[t] = dpp_fadd<0x118>(o[t]);   // row_shr:8
      o[t] = dpp_fadd<0x114>(o[t]);   // row_shr:4
      o[t] = dpp_fadd<0x112>(o[t]);   // row_shr:2
      o[t] = dpp_fadd<0x111>(o[t]);   // row_shr:1
    }

    if (lr == 15) {
      float* op = out + (long)n * 64;
      *(float4*)(op + g * 8)      = make_float4(o[0],  o[1],  o[2],  o[3]);
      *(float4*)(op + g * 8 + 4)  = make_float4(o[4],  o[5],  o[6],  o[7]);
      *(float4*)(op + 32 + g * 8) = make_float4(o[8],  o[9],  o[10], o[11]);
      *(float4*)(op + 36 + g * 8) = make_float4(o[12], o[13], o[14], o[15]);
    }
  }
}

extern "C" void kernel_launch(void* const* d_in, const int* in_sizes, int n_in,
                              void* d_out, int out_size, void* d_ws, size_t ws_size,
                              hipStream_t stream) {
  const float* emb = (const float*)d_in[0];
  const float* W1  = (const float*)d_in[1];
  const float* b1  = (const float*)d_in[2];
  const float* W2  = (const float*)d_in[3];
  const float* b2  = (const float*)d_in[4];
  const float* w3  = (const float*)d_in[5];
  const float* b3  = (const float*)d_in[6];
  const int* vn = (const int*)d_in[7];
  const int* ni = (const int*)d_in[8];
  const int* nd = (const int*)d_in[9];
  float* out = (float*)d_out;
  const int N = in_sizes[7];
  __bf16* wf = (__bf16*)d_ws;   // 24576 B

  prep_frags<<<48, 256, 0, stream>>>(W1, W2, wf);
  graph_agg<<<1024, 512, 0, stream>>>(emb, b1, b2, w3, b3, vn, ni, nd, wf, out, N);
}

// Round 4
// 131.558 us; speedup vs baseline: 1.4246x; 1.4246x over previous
//
#include <hip/hip_runtime.h>
#include <hip/hip_bf16.h>

typedef __bf16 bf16x8 __attribute__((ext_vector_type(8)));
typedef float  f32x4  __attribute__((ext_vector_type(4)));

#define MFMA32(acc, a, b) acc = __builtin_amdgcn_mfma_f32_16x16x32_bf16(a, b, acc, 0, 0, 0)

__device__ __forceinline__ bf16x8 cvt8(float4 a, float4 b) {
  bf16x8 r;
  r[0] = (__bf16)a.x; r[1] = (__bf16)a.y; r[2] = (__bf16)a.z; r[3] = (__bf16)a.w;
  r[4] = (__bf16)b.x; r[5] = (__bf16)b.y; r[6] = (__bf16)b.z; r[7] = (__bf16)b.w;
  return r;
}

// DPP-based in-row (16-lane) reductions.  row_shr:N = 0x110|N (to-lane-15 reduce,
// OOB lanes read 0 via bound_ctrl), row_ror:N = 0x120|N (all-lane butterfly).
template <int CTRL>
__device__ __forceinline__ float dpp_fadd(float x) {
  int yi = __builtin_amdgcn_update_dpp(0, __builtin_bit_cast(int, x), CTRL, 0xF, 0xF, true);
  return x + __builtin_bit_cast(float, yi);
}
template <int CTRL>
__device__ __forceinline__ float dpp_fmax(float x) {
  int yi = __builtin_amdgcn_update_dpp(0, __builtin_bit_cast(int, x), CTRL, 0xF, 0xF, true);
  return fmaxf(x, __builtin_bit_cast(float, yi));
}

// W1frag [ks=4][mt=4][lane][j=8]: A-frag of W1^T:
//   = W1[(ks*32 + (lane>>4)*8 + j)][mt*16 + (lane&15)]
// W2frag [ks2=2][mt2=4][lane][j=8]: A-frag of W2^T with PERMUTED k-axis
//   rho(ks2,g,j) = (ks2*2 + (j>>2))*16 + g*4 + (j&3)   (g = lane>>4)
//   = W2[rho][mt2*16 + (lane&15)]
// Same rho used when building layer-2 B-frags from in-register layer-1 accs.
__global__ void prep_frags(const float* __restrict__ W1,
                           const float* __restrict__ W2,
                           __bf16* __restrict__ wf) {
  int idx = blockIdx.x * 256 + threadIdx.x;
  if (idx < 8192) {
    int j = idx & 7, lane = (idx >> 3) & 63, mt = (idx >> 9) & 3, ks = idx >> 11;
    int i = ks * 32 + ((lane >> 4) << 3) + j;
    int col = mt * 16 + (lane & 15);
    wf[idx] = (__bf16)W1[i * 64 + col];
  } else if (idx < 12288) {
    int t = idx - 8192;
    int j = t & 7, lane = (t >> 3) & 63, mt2 = (t >> 9) & 3, ks2 = (t >> 11) & 1;
    int g = (lane >> 4) & 3;
    int rho = (ks2 * 2 + (j >> 2)) * 16 + g * 4 + (j & 3);
    wf[idx] = (__bf16)W2[rho * 64 + mt2 * 16 + (lane & 15)];
  }
}

// One wave per node, 512 threads = 8 waves/block.
// __launch_bounds__(512, 6): VGPR cap ~84 — high occupancy WITHOUT spills
// (R3's (512,8) forced VGPR<=64 -> 349 MB scratch spill traffic, 2.2x regression).
// LDS: [0,16384) W1frag  [16384,24576) W2frag
//      [24576,24832) b1 f32  [24832,25088) b2 f32  [25088,25344) w3 f32
__global__ __launch_bounds__(512, 6) void graph_agg(
    const float* __restrict__ emb,
    const float* __restrict__ b1g,
    const float* __restrict__ b2g,
    const float* __restrict__ w3g,
    const float* __restrict__ b3g,
    const int* __restrict__ vn,
    const int* __restrict__ ni,
    const int* __restrict__ nd,
    const __bf16* __restrict__ wf,
    float* __restrict__ out,
    int N) {
  __shared__ __align__(16) unsigned char smem[25344];

  {
    const uint4* src = (const uint4*)wf;
    uint4* dst = (uint4*)smem;
#pragma unroll
    for (int i = 0; i < 3; i++) dst[threadIdx.x + i * 512] = src[threadIdx.x + i * 512];
    int t = threadIdx.x;
    if (t < 64) {
      ((float*)(smem + 24576))[t] = b1g[t];
      ((float*)(smem + 24832))[t] = b2g[t];
      ((float*)(smem + 25088))[t] = w3g[t];
    }
  }
  __syncthreads();

  const __bf16* w1f = (const __bf16*)smem;
  const __bf16* w2f = (const __bf16*)(smem + 16384);
  const int wid = threadIdx.x >> 6;
  const int l   = threadIdx.x & 63;
  const int g   = l >> 4;
  const int lr  = l & 15;
  const float b3v = b3g[0];

  const int gw = blockIdx.x * 8 + wid;
  const int nwaves = gridDim.x * 8;

  int n = gw;
  int node = 0, deg = 0, i0 = 0, i1 = 0;
  if (n < N) {
    node = vn[n]; deg = nd[n];
    i0 = ni[n * 32 + lr]; i1 = ni[n * 32 + 16 + lr];
  }

  for (; n < N; n += nwaves) {
    const int cn = node, cd = deg, ci0 = i0, ci1 = i1;
    {  // prefetch next iteration's scalars/indices
      int nn = n + nwaves; if (nn >= N) nn = n;
      node = vn[nn]; deg = nd[nn];
      i0 = ni[nn * 32 + lr]; i1 = ni[nn * 32 + 16 + lr];
    }
    const float* ub = emb + (long)cn * 64;

    if (cd == 0) {                 // no neighbors: copy own embedding
      out[(long)n * 64 + l] = ub[l];
      continue;
    }
    const bool m1 = (cd > 16);

    int boff = 24576;
    asm volatile("" : "+v"(boff));   // opaque: keep bias reads per-iteration (in LDS, not regs)
    const unsigned char* bb = smem + boff;

    // ---- gather: B-frags of X^T.  ef[nt][ks][j] = e[neigh[nt*16+lr]][ks*32+g*8+j]
    bf16x8 ef[2][2];
    bf16x8 uf[2];
    {
      const bool v = (lr < cd);
      const float* p = emb + (long)(v ? ci0 : cn) * 64 + g * 8;
      float4 a0 = *(const float4*)p,        a1 = *(const float4*)(p + 4);
      float4 c0 = *(const float4*)(p + 32), c1 = *(const float4*)(p + 36);
      if (!v) { a0 = a1 = c0 = c1 = make_float4(0.f, 0.f, 0.f, 0.f); }
      ef[0][0] = cvt8(a0, a1); ef[0][1] = cvt8(c0, c1);
    }
    if (m1) {
      const bool v = (16 + lr < cd);
      const float* p = emb + (long)(v ? ci1 : cn) * 64 + g * 8;
      float4 a0 = *(const float4*)p,        a1 = *(const float4*)(p + 4);
      float4 c0 = *(const float4*)(p + 32), c1 = *(const float4*)(p + 36);
      if (!v) { a0 = a1 = c0 = c1 = make_float4(0.f, 0.f, 0.f, 0.f); }
      ef[1][0] = cvt8(a0, a1); ef[1][1] = cvt8(c0, c1);
    }
    {
      const float* q = ub + g * 8;
      uf[0] = cvt8(*(const float4*)q,        *(const float4*)(q + 4));
      uf[1] = cvt8(*(const float4*)(q + 32), *(const float4*)(q + 36));
    }

    // ---- layer 1: C1t[64][32] = W1^T @ X^T  (acc init = b1 broadcast) ----
    f32x4 acc1[4][2];
#pragma unroll
    for (int mt = 0; mt < 4; mt++) {
      f32x4 bv = *(const f32x4*)(bb + (mt * 16 + g * 4) * 4);
      acc1[mt][0] = bv; acc1[mt][1] = bv;
    }
#pragma unroll
    for (int ks = 0; ks < 4; ks++) {
      bf16x8 xb0 = (ks < 2) ? ef[0][ks] : uf[ks - 2];
#pragma unroll
      for (int mt = 0; mt < 4; mt++) {
        bf16x8 wa = *(const bf16x8*)(w1f + ((ks * 4 + mt) * 64 + l) * 8);
        MFMA32(acc1[mt][0], wa, xb0);
        if (m1) {
          bf16x8 xb1 = (ks < 2) ? ef[1][ks] : uf[ks - 2];
          MFMA32(acc1[mt][1], wa, xb1);
        }
      }
    }

    // ---- relu -> bf16 B-frags for layer 2, permuted k-axis (in-register) ----
    bf16x8 hb[2][2];
#pragma unroll
    for (int ks2 = 0; ks2 < 2; ks2++) {
#pragma unroll
      for (int nt = 0; nt < 2; nt++) {
        if (nt == 0 || m1) {
          bf16x8 v;
#pragma unroll
          for (int j = 0; j < 8; j++) {
            const int mt = ks2 * 2 + (j >> 2), r = j & 3;
            v[j] = (__bf16)fmaxf(acc1[mt][nt][r], 0.f);
          }
          hb[ks2][nt] = v;
        }
      }
    }

    // ---- layer 2: C2t[64][32] = W2^T @ H1t (acc init = b2) ----
    f32x4 acc2[4][2];
#pragma unroll
    for (int mt2 = 0; mt2 < 4; mt2++) {
      f32x4 bv = *(const f32x4*)(bb + 256 + (mt2 * 16 + g * 4) * 4);
      acc2[mt2][0] = bv; acc2[mt2][1] = bv;
    }
#pragma unroll
    for (int ks2 = 0; ks2 < 2; ks2++) {
#pragma unroll
      for (int mt2 = 0; mt2 < 4; mt2++) {
        bf16x8 wa = *(const bf16x8*)(w2f + ((ks2 * 4 + mt2) * 64 + l) * 8);
        MFMA32(acc2[mt2][0], wa, hb[ks2][0]);
        if (m1) MFMA32(acc2[mt2][1], wa, hb[ks2][1]);
      }
    }

    // ---- scores: s[nb] = relu(C2t+b2) . w3 + b3 (partial over 16 in-lane h2 dims) ----
    float sv0 = 0.f, sv1 = 0.f;
    {
#pragma unroll
      for (int mt2 = 0; mt2 < 4; mt2++) {
        f32x4 wv = *(const f32x4*)(bb + 512 + (mt2 * 16 + g * 4) * 4);
#pragma unroll
        for (int r = 0; r < 4; r++) {
          sv0 += fmaxf(acc2[mt2][0][r], 0.f) * wv[r];
          if (m1) sv1 += fmaxf(acc2[mt2][1][r], 0.f) * wv[r];
        }
      }
    }
    sv0 += __shfl_xor(sv0, 16); sv0 += __shfl_xor(sv0, 32);
    if (m1) { sv1 += __shfl_xor(sv1, 16); sv1 += __shfl_xor(sv1, 32); }

    const bool v0 = (lr < cd);
    const bool v1 = m1 && (16 + lr < cd);
    sv0 = v0 ? (sv0 + b3v) : -1e30f;
    sv1 = v1 ? (sv1 + b3v) : -1e30f;

    // ---- softmax over 32 neighbors (neighbor = lr within each 16-row) ----
    float mx = fmaxf(sv0, sv1);
    mx = dpp_fmax<0x128>(mx);   // row_ror:8
    mx = dpp_fmax<0x124>(mx);   // row_ror:4
    mx = dpp_fmax<0x122>(mx);   // row_ror:2
    mx = dpp_fmax<0x121>(mx);   // row_ror:1

    float p0 = v0 ? __expf(sv0 - mx) : 0.f;
    float p1 = v1 ? __expf(sv1 - mx) : 0.f;
    float sum = p0 + p1;
    sum = dpp_fadd<0x128>(sum);
    sum = dpp_fadd<0x124>(sum);
    sum = dpp_fadd<0x122>(sum);
    sum = dpp_fadd<0x121>(sum);
    const float inv = 1.f / sum;
    const float a0 = p0 * inv, a1 = p1 * inv;

    // ---- out[d] = sum_k att[k]*e[k][d]: in-lane over nt, DPP row_shr tree over lr
    //      (result lands in lane 15 of each 16-row) ----
    float o[16];
#pragma unroll
    for (int ks = 0; ks < 2; ks++)
#pragma unroll
      for (int j = 0; j < 8; j++) {
        float v = a0 * (float)ef[0][ks][j];
        if (m1) v += a1 * (float)ef[1][ks][j];
        o[ks * 8 + j] = v;
      }
#pragma unroll
    for (int t = 0; t < 16; t++) {
      o[t] = dpp_fadd<0x118>(o[t]);   // row_shr:8
      o[t] = dpp_fadd<0x114>(o[t]);   // row_shr:4
      o[t] = dpp_fadd<0x112>(o[t]);   // row_shr:2
      o[t] = dpp_fadd<0x111>(o[t]);   // row_shr:1
    }

    if (lr == 15) {
      float* op = out + (long)n * 64;
      *(float4*)(op + g * 8)      = make_float4(o[0],  o[1],  o[2],  o[3]);
      *(float4*)(op + g * 8 + 4)  = make_float4(o[4],  o[5],  o[6],  o[7]);
      *(float4*)(op + 32 + g * 8) = make_float4(o[8],  o[9],  o[10], o[11]);
      *(float4*)(op + 36 + g * 8) = make_float4(o[12], o[13], o[14], o[15]);
    }
  }
}

extern "C" void kernel_launch(void* const* d_in, const int* in_sizes, int n_in,
                              void* d_out, int out_size, void* d_ws, size_t ws_size,
                              hipStream_t stream) {
  const float* emb = (const float*)d_in[0];
  const float* W1  = (const float*)d_in[1];
  const float* b1  = (const float*)d_in[2];
  const float* W2  = (const float*)d_in[3];
  const float* b2  = (const float*)d_in[4];
  const float* w3  = (const float*)d_in[5];
  const float* b3  = (const float*)d_in[6];
  const int* vn = (const int*)d_in[7];
  const int* ni = (const int*)d_in[8];
  const int* nd = (const int*)d_in[9];
  float* out = (float*)d_out;
  const int N = in_sizes[7];
  __bf16* wf = (__bf16*)d_ws;   // 24576 B

  prep_frags<<<48, 256, 0, stream>>>(W1, W2, wf);
  graph_agg<<<1024, 512, 0, stream>>>(emb, b1, b2, w3, b3, vn, ni, nd, wf, out, N);
}

// Round 5
// 76.604 us; speedup vs baseline: 2.4465x; 1.7174x over previous
//
#include <hip/hip_runtime.h>
#include <hip/hip_bf16.h>

typedef __bf16 bf16x8 __attribute__((ext_vector_type(8)));
typedef float  f32x4  __attribute__((ext_vector_type(4)));

#define MFMA32(acc, a, b) acc = __builtin_amdgcn_mfma_f32_16x16x32_bf16(a, b, acc, 0, 0, 0)

__device__ __forceinline__ bf16x8 cvt8(float4 a, float4 b) {
  bf16x8 r;
  r[0] = (__bf16)a.x; r[1] = (__bf16)a.y; r[2] = (__bf16)a.z; r[3] = (__bf16)a.w;
  r[4] = (__bf16)b.x; r[5] = (__bf16)b.y; r[6] = (__bf16)b.z; r[7] = (__bf16)b.w;
  return r;
}

// DPP-based in-row (16-lane) reductions.  row_shr:N = 0x110|N (to-lane-15 reduce,
// OOB lanes read 0 via bound_ctrl), row_ror:N = 0x120|N (all-lane butterfly).
template <int CTRL>
__device__ __forceinline__ float dpp_fadd(float x) {
  int yi = __builtin_amdgcn_update_dpp(0, __builtin_bit_cast(int, x), CTRL, 0xF, 0xF, true);
  return x + __builtin_bit_cast(float, yi);
}
template <int CTRL>
__device__ __forceinline__ float dpp_fmax(float x) {
  int yi = __builtin_amdgcn_update_dpp(0, __builtin_bit_cast(int, x), CTRL, 0xF, 0xF, true);
  return fmaxf(x, __builtin_bit_cast(float, yi));
}

// W1frag [ks=4][mt=4][lane][j=8]: A-frag of W1^T:
//   = W1[(ks*32 + (lane>>4)*8 + j)][mt*16 + (lane&15)]
// W2frag [ks2=2][mt2=4][lane][j=8]: A-frag of W2^T with PERMUTED k-axis
//   rho(ks2,g,j) = (ks2*2 + (j>>2))*16 + g*4 + (j&3)   (g = lane>>4)
//   = W2[rho][mt2*16 + (lane&15)]
// Same rho used when building layer-2 B-frags from in-register layer-1 accs.
__global__ void prep_frags(const float* __restrict__ W1,
                           const float* __restrict__ W2,
                           __bf16* __restrict__ wf) {
  int idx = blockIdx.x * 256 + threadIdx.x;
  if (idx < 8192) {
    int j = idx & 7, lane = (idx >> 3) & 63, mt = (idx >> 9) & 3, ks = idx >> 11;
    int i = ks * 32 + ((lane >> 4) << 3) + j;
    int col = mt * 16 + (lane & 15);
    wf[idx] = (__bf16)W1[i * 64 + col];
  } else if (idx < 12288) {
    int t = idx - 8192;
    int j = t & 7, lane = (t >> 3) & 63, mt2 = (t >> 9) & 3, ks2 = (t >> 11) & 1;
    int g = (lane >> 4) & 3;
    int rho = (ks2 * 2 + (j >> 2)) * 16 + g * 4 + (j & 3);
    wf[idx] = (__bf16)W2[rho * 64 + mt2 * 16 + (lane & 15)];
  }
}

// One wave per node, 512 threads = 8 waves/block.
// NO min-waves bound: R3's (512,8) => VGPR<=64 forced 349 MB spill writes;
// R4's (512,6) => compiler rematerialized ef[] (VGPR 40, +62 MB re-gather FETCH).
// Unbounded, this body compiles to ~52 VGPR (measured R2) <= 64 -> 8 waves/SIMD
// naturally; LDS 25.3 KB * 4 blocks = 101 KB <= 160 KB -> 32 waves/CU.
// LDS: [0,16384) W1frag  [16384,24576) W2frag
//      [24576,24832) b1 f32  [24832,25088) b2 f32  [25088,25344) w3 f32
__global__ __launch_bounds__(512) void graph_agg(
    const float* __restrict__ emb,
    const float* __restrict__ b1g,
    const float* __restrict__ b2g,
    const float* __restrict__ w3g,
    const float* __restrict__ b3g,
    const int* __restrict__ vn,
    const int* __restrict__ ni,
    const int* __restrict__ nd,
    const __bf16* __restrict__ wf,
    float* __restrict__ out,
    int N) {
  __shared__ __align__(16) unsigned char smem[25344];

  {
    const uint4* src = (const uint4*)wf;
    uint4* dst = (uint4*)smem;
#pragma unroll
    for (int i = 0; i < 3; i++) dst[threadIdx.x + i * 512] = src[threadIdx.x + i * 512];
    int t = threadIdx.x;
    if (t < 64) {
      ((float*)(smem + 24576))[t] = b1g[t];
      ((float*)(smem + 24832))[t] = b2g[t];
      ((float*)(smem + 25088))[t] = w3g[t];
    }
  }
  __syncthreads();

  const __bf16* w1f = (const __bf16*)smem;
  const __bf16* w2f = (const __bf16*)(smem + 16384);
  const int wid = threadIdx.x >> 6;
  const int l   = threadIdx.x & 63;
  const int g   = l >> 4;
  const int lr  = l & 15;
  const float b3v = b3g[0];

  const int gw = blockIdx.x * 8 + wid;
  const int nwaves = gridDim.x * 8;

  int n = gw;
  int node = 0, deg = 0, i0 = 0, i1 = 0;
  if (n < N) {
    node = vn[n]; deg = nd[n];
    i0 = ni[n * 32 + lr]; i1 = ni[n * 32 + 16 + lr];
  }

  for (; n < N; n += nwaves) {
    const int cn = node, cd = deg, ci0 = i0, ci1 = i1;
    {  // prefetch next iteration's scalars/indices
      int nn = n + nwaves; if (nn >= N) nn = n;
      node = vn[nn]; deg = nd[nn];
      i0 = ni[nn * 32 + lr]; i1 = ni[nn * 32 + 16 + lr];
    }
    const float* ub = emb + (long)cn * 64;

    if (cd == 0) {                 // no neighbors: copy own embedding
      out[(long)n * 64 + l] = ub[l];
      continue;
    }
    const bool m1 = (cd > 16);

    int boff = 24576;
    asm volatile("" : "+v"(boff));   // opaque: keep bias reads per-iteration (in LDS, not regs)
    const unsigned char* bb = smem + boff;

    // ---- gather: B-frags of X^T.  ef[nt][ks][j] = e[neigh[nt*16+lr]][ks*32+g*8+j]
    bf16x8 ef[2][2];
    bf16x8 uf[2];
    {
      const bool v = (lr < cd);
      const float* p = emb + (long)(v ? ci0 : cn) * 64 + g * 8;
      float4 a0 = *(const float4*)p,        a1 = *(const float4*)(p + 4);
      float4 c0 = *(const float4*)(p + 32), c1 = *(const float4*)(p + 36);
      if (!v) { a0 = a1 = c0 = c1 = make_float4(0.f, 0.f, 0.f, 0.f); }
      ef[0][0] = cvt8(a0, a1); ef[0][1] = cvt8(c0, c1);
    }
    if (m1) {
      const bool v = (16 + lr < cd);
      const float* p = emb + (long)(v ? ci1 : cn) * 64 + g * 8;
      float4 a0 = *(const float4*)p,        a1 = *(const float4*)(p + 4);
      float4 c0 = *(const float4*)(p + 32), c1 = *(const float4*)(p + 36);
      if (!v) { a0 = a1 = c0 = c1 = make_float4(0.f, 0.f, 0.f, 0.f); }
      ef[1][0] = cvt8(a0, a1); ef[1][1] = cvt8(c0, c1);
    }
    {
      const float* q = ub + g * 8;
      uf[0] = cvt8(*(const float4*)q,        *(const float4*)(q + 4));
      uf[1] = cvt8(*(const float4*)(q + 32), *(const float4*)(q + 36));
    }

    // ---- layer 1: C1t[64][32] = W1^T @ X^T  (acc init = b1 broadcast) ----
    f32x4 acc1[4][2];
#pragma unroll
    for (int mt = 0; mt < 4; mt++) {
      f32x4 bv = *(const f32x4*)(bb + (mt * 16 + g * 4) * 4);
      acc1[mt][0] = bv; acc1[mt][1] = bv;
    }
#pragma unroll
    for (int ks = 0; ks < 4; ks++) {
      bf16x8 xb0 = (ks < 2) ? ef[0][ks] : uf[ks - 2];
#pragma unroll
      for (int mt = 0; mt < 4; mt++) {
        bf16x8 wa = *(const bf16x8*)(w1f + ((ks * 4 + mt) * 64 + l) * 8);
        MFMA32(acc1[mt][0], wa, xb0);
        if (m1) {
          bf16x8 xb1 = (ks < 2) ? ef[1][ks] : uf[ks - 2];
          MFMA32(acc1[mt][1], wa, xb1);
        }
      }
    }

    // ---- relu -> bf16 B-frags for layer 2, permuted k-axis (in-register) ----
    bf16x8 hb[2][2];
#pragma unroll
    for (int ks2 = 0; ks2 < 2; ks2++) {
#pragma unroll
      for (int nt = 0; nt < 2; nt++) {
        if (nt == 0 || m1) {
          bf16x8 v;
#pragma unroll
          for (int j = 0; j < 8; j++) {
            const int mt = ks2 * 2 + (j >> 2), r = j & 3;
            v[j] = (__bf16)fmaxf(acc1[mt][nt][r], 0.f);
          }
          hb[ks2][nt] = v;
        }
      }
    }

    // ---- layer 2: C2t[64][32] = W2^T @ H1t (acc init = b2) ----
    f32x4 acc2[4][2];
#pragma unroll
    for (int mt2 = 0; mt2 < 4; mt2++) {
      f32x4 bv = *(const f32x4*)(bb + 256 + (mt2 * 16 + g * 4) * 4);
      acc2[mt2][0] = bv; acc2[mt2][1] = bv;
    }
#pragma unroll
    for (int ks2 = 0; ks2 < 2; ks2++) {
#pragma unroll
      for (int mt2 = 0; mt2 < 4; mt2++) {
        bf16x8 wa = *(const bf16x8*)(w2f + ((ks2 * 4 + mt2) * 64 + l) * 8);
        MFMA32(acc2[mt2][0], wa, hb[ks2][0]);
        if (m1) MFMA32(acc2[mt2][1], wa, hb[ks2][1]);
      }
    }

    // ---- scores: s[nb] = relu(C2t+b2) . w3 + b3 (partial over 16 in-lane h2 dims) ----
    float sv0 = 0.f, sv1 = 0.f;
    {
#pragma unroll
      for (int mt2 = 0; mt2 < 4; mt2++) {
        f32x4 wv = *(const f32x4*)(bb + 512 + (mt2 * 16 + g * 4) * 4);
#pragma unroll
        for (int r = 0; r < 4; r++) {
          sv0 += fmaxf(acc2[mt2][0][r], 0.f) * wv[r];
          if (m1) sv1 += fmaxf(acc2[mt2][1][r], 0.f) * wv[r];
        }
      }
    }
    sv0 += __shfl_xor(sv0, 16); sv0 += __shfl_xor(sv0, 32);
    if (m1) { sv1 += __shfl_xor(sv1, 16); sv1 += __shfl_xor(sv1, 32); }

    const bool v0 = (lr < cd);
    const bool v1 = m1 && (16 + lr < cd);
    sv0 = v0 ? (sv0 + b3v) : -1e30f;
    sv1 = v1 ? (sv1 + b3v) : -1e30f;

    // ---- softmax over 32 neighbors (neighbor = lr within each 16-row) ----
    float mx = fmaxf(sv0, sv1);
    mx = dpp_fmax<0x128>(mx);   // row_ror:8
    mx = dpp_fmax<0x124>(mx);   // row_ror:4
    mx = dpp_fmax<0x122>(mx);   // row_ror:2
    mx = dpp_fmax<0x121>(mx);   // row_ror:1

    float p0 = v0 ? __expf(sv0 - mx) : 0.f;
    float p1 = v1 ? __expf(sv1 - mx) : 0.f;
    float sum = p0 + p1;
    sum = dpp_fadd<0x128>(sum);
    sum = dpp_fadd<0x124>(sum);
    sum = dpp_fadd<0x122>(sum);
    sum = dpp_fadd<0x121>(sum);
    const float inv = 1.f / sum;
    const float a0 = p0 * inv, a1 = p1 * inv;

    // ---- out[d] = sum_k att[k]*e[k][d]: in-lane over nt, DPP row_shr tree over lr
    //      (result lands in lane 15 of each 16-row) ----
    float o[16];
#pragma unroll
    for (int ks = 0; ks < 2; ks++)
#pragma unroll
      for (int j = 0; j < 8; j++) {
        float v = a0 * (float)ef[0][ks][j];
        if (m1) v += a1 * (float)ef[1][ks][j];
        o[ks * 8 + j] = v;
      }
#pragma unroll
    for (int t = 0; t < 16; t++) {
      o[t] = dpp_fadd<0x118>(o[t]);   // row_shr:8
      o[t] = dpp_fadd<0x114>(o[t]);   // row_shr:4
      o[t] = dpp_fadd<0x112>(o[t]);   // row_shr:2
      o[t] = dpp_fadd<0x111>(o[t]);   // row_shr:1
    }

    if (lr == 15) {
      float* op = out + (long)n * 64;
      *(float4*)(op + g * 8)      = make_float4(o[0],  o[1],  o[2],  o[3]);
      *(float4*)(op + g * 8 + 4)  = make_float4(o[4],  o[5],  o[6],  o[7]);
      *(float4*)(op + 32 + g * 8) = make_float4(o[8],  o[9],  o[10], o[11]);
      *(float4*)(op + 36 + g * 8) = make_float4(o[12], o[13], o[14], o[15]);
    }
  }
}

extern "C" void kernel_launch(void* const* d_in, const int* in_sizes, int n_in,
                              void* d_out, int out_size, void* d_ws, size_t ws_size,
                              hipStream_t stream) {
  const float* emb = (const float*)d_in[0];
  const float* W1  = (const float*)d_in[1];
  const float* b1  = (const float*)d_in[2];
  const float* W2  = (const float*)d_in[3];
  const float* b2  = (const float*)d_in[4];
  const float* w3  = (const float*)d_in[5];
  const float* b3  = (const float*)d_in[6];
  const int* vn = (const int*)d_in[7];
  const int* ni = (const int*)d_in[8];
  const int* nd = (const int*)d_in[9];
  float* out = (float*)d_out;
  const int N = in_sizes[7];
  __bf16* wf = (__bf16*)d_ws;   // 24576 B

  prep_frags<<<48, 256, 0, stream>>>(W1, W2, wf);
  graph_agg<<<1024, 512, 0, stream>>>(emb, b1, b2, w3, b3, vn, ni, nd, wf, out, N);
}